// Round 3
// baseline (13137.588 us; speedup 1.0000x reference)
//
#include <hip/hip_runtime.h>
#include <cstdint>
#include <cstddef>

#define Dm 768
#define Hh 12
#define DHd 64
#define Ll 12
#define Vv 50257
#define Tt 4096
#define Ff 3072
#define ETA (1.0f/16.0f)

typedef __attribute__((ext_vector_type(8))) short bf16x8;
typedef __attribute__((ext_vector_type(8))) unsigned short ushort8;
typedef __attribute__((ext_vector_type(4))) float f32x4;

static __device__ __forceinline__ unsigned short f2bf(float f){
  union { float f; unsigned int u; } v; v.f = f;
  unsigned int r = v.u + 0x7fffu + ((v.u >> 16) & 1u);
  return (unsigned short)(r >> 16);
}
// returns (hi<<16)|lo : hi=bf16(f), lo=bf16(f - hi); hi+lo carries ~16 mantissa bits
static __device__ __forceinline__ unsigned int split_bf(float f){
  const unsigned short h = f2bf(f);
  union { unsigned int u; float f; } vh; vh.u = ((unsigned int)h) << 16;
  const unsigned short l = f2bf(f - vh.f);
  return (((unsigned int)h) << 16) | (unsigned int)l;
}

// ---------------- LayerNorm (optional embedding gather via ids) ----------------
__global__ __launch_bounds__(256)
void ln_kernel(const float* __restrict__ in, const int* __restrict__ ids,
               const float* __restrict__ w, const float* __restrict__ b,
               float* __restrict__ out)
{
  const int row = blockIdx.x;
  const int t = threadIdx.x;
  const float* px = in + (ids ? (size_t)ids[row] * Dm : (size_t)row * Dm);
  float x0 = px[t], x1 = px[t+256], x2 = px[t+512];
  float s  = x0 + x1 + x2;
  float s2 = x0*x0 + x1*x1 + x2*x2;
  #pragma unroll
  for (int o = 32; o > 0; o >>= 1) { s += __shfl_xor(s, o); s2 += __shfl_xor(s2, o); }
  __shared__ float ls[4], ls2[4];
  if ((t & 63) == 0) { ls[t>>6] = s; ls2[t>>6] = s2; }
  __syncthreads();
  s  = ls[0]+ls[1]+ls[2]+ls[3];
  s2 = ls2[0]+ls2[1]+ls2[2]+ls2[3];
  const float mu  = s * (1.0f/Dm);
  const float var = s2 * (1.0f/Dm) - mu*mu;
  const float rs  = rsqrtf(var + 1e-5f);
  float* po = out + (size_t)row * Dm;
  po[t]     = (x0-mu)*rs*w[t]     + b[t];
  po[t+256] = (x1-mu)*rs*w[t+256] + b[t+256];
  po[t+512] = (x2-mu)*rs*w[t+512] + b[t+512];
}

// ---------------- RoPE (in-place on q and k) ----------------
__global__ __launch_bounds__(256)
void rope_kernel(float* __restrict__ q, float* __restrict__ k)
{
  const int gid = blockIdx.x * 256 + threadIdx.x;
  if (gid >= Tt * Hh * 32) return;
  const int tkn = gid / (Hh * 32);
  const int r   = gid - tkn * (Hh * 32);
  const int hh  = r >> 5;
  const int d   = r & 31;
  const int s   = tkn & 1023;
  const float freq = 1.0f / powf(10000.0f, (float)d * (1.0f/32.0f));
  const float ang  = (float)s * freq;
  const float c = cosf(ang), sn = sinf(ang);
  const size_t base = (size_t)tkn * Dm + hh * DHd + d;
  float a1 = q[base], a2 = q[base + 32];
  q[base]      = a1*c - a2*sn;
  q[base + 32] = a1*sn + a2*c;
  float b1 = k[base], b2 = k[base + 32];
  k[base]      = b1*c - b2*sn;
  k[base + 32] = b1*sn + b2*c;
}

// ---------------- TTT chunked scan: one block per (b,h), f32 in LDS ----------------
// Writes O in place over q.
__global__ __launch_bounds__(256)
void ttt_scan_kernel(float* __restrict__ qo, const float* __restrict__ kk,
                     const float* __restrict__ vv)
{
  const int b  = blockIdx.x / Hh;
  const int hd = blockIdx.x % Hh;
  const int t  = threadIdx.x;
  __shared__ float Wm[64][64];    // W[d][e]
  __shared__ float kms[16][68];   // padded to kill bank conflicts in A-phase
  __shared__ float qms[16][68];
  __shared__ float Es[16][64];
  __shared__ float Asc[16][16];

  for (int i = t; i < 4096; i += 256) Wm[i>>6][i&63] = 0.0f;
  __syncthreads();

  for (int c = 0; c < 64; ++c) {
    const int tb = b*1024 + c*16;
    for (int i = t; i < 1024; i += 256) {
      const int m = i >> 6, d = i & 63;
      const size_t gidx = (size_t)(tb+m)*Dm + hd*DHd + d;
      kms[m][d] = kk[gidx];
      qms[m][d] = qo[gidx];
    }
    __syncthreads();
    // phase 2: E = km@W - vm ; Oq = qm@W ; A = (qm@km^T)*tril*(-eta)
    float Oq[4];
    #pragma unroll
    for (int i = 0; i < 4; ++i) {
      const int m = (t >> 6) + 4*i;
      const int e = t & 63;
      float aE = -vv[(size_t)(tb+m)*Dm + hd*DHd + e];
      float aO = 0.0f;
      for (int d = 0; d < 64; ++d) {
        const float wv_ = Wm[d][e];
        aE += kms[m][d] * wv_;
        aO += qms[m][d] * wv_;
      }
      Es[m][e] = aE;
      Oq[i] = aO;
    }
    {
      const int m = t >> 4, n = t & 15;
      float a = 0.0f;
      for (int d = 0; d < 64; ++d) a += qms[m][d] * kms[n][d];
      Asc[m][n] = (n <= m) ? (-ETA * a) : 0.0f;
    }
    __syncthreads();
    // phase 3: O = Oq + A@E (A pre-scaled by -eta); W -= eta*km^T@E
    #pragma unroll
    for (int i = 0; i < 4; ++i) {
      const int m = (t >> 6) + 4*i;
      const int e = t & 63;
      float acc = Oq[i];
      #pragma unroll
      for (int n = 0; n < 16; ++n) acc += Asc[m][n] * Es[n][e];
      qo[(size_t)(tb+m)*Dm + hd*DHd + e] = acc;
    }
    #pragma unroll
    for (int i = 0; i < 16; ++i) {
      const int d = (t >> 6) + 4*i;
      const int e = t & 63;
      float a = 0.0f;
      #pragma unroll
      for (int m = 0; m < 16; ++m) a += kms[m][d] * Es[m][e];
      Wm[d][e] -= ETA * a;
    }
    __syncthreads();
  }
}

// ---------------- split-bf16 MFMA GEMM, 64x64x64 tile, 2x2 waves ----------------
// C[M,N] = A[M,K] @ op(B) (+bias)(+gelu)(+res). TB: B is [N,K] (C=A@B^T).
// f32 operands split into hi+lo bf16; acc = hi*hi + hi*lo + lo*hi (~fp32 accuracy).
static __device__ __forceinline__ float gelu_f(float x){
  const float u = 0.7978845608028654f * (x + 0.044715f * x*x*x);
  return 0.5f * x * (1.0f + tanhf(u));
}

template<bool TB, bool BIAS, bool GELU_, bool RES>
__global__ __launch_bounds__(256)
void gemm_kernel(const float* __restrict__ A, const float* __restrict__ B,
                 const float* __restrict__ bias, const float* __restrict__ res,
                 float* __restrict__ C, int M, int N, int K)
{
  __shared__ __attribute__((aligned(16))) unsigned short AsH[64][72];
  __shared__ __attribute__((aligned(16))) unsigned short AsL[64][72];
  __shared__ __attribute__((aligned(16))) unsigned short BsH[64][72];
  __shared__ __attribute__((aligned(16))) unsigned short BsL[64][72];
  const int t    = threadIdx.x;
  const int lane = t & 63;
  const int fr   = lane & 15;
  const int fg   = lane >> 4;
  const int wave = t >> 6;
  const int wm   = (wave >> 1) * 32;
  const int wn   = (wave & 1) * 32;
  const int row0 = blockIdx.y * 64;
  const int n0   = blockIdx.x * 64;

  f32x4 acc[2][2];
  #pragma unroll
  for (int i = 0; i < 2; ++i)
    #pragma unroll
    for (int j = 0; j < 2; ++j)
      #pragma unroll
      for (int r = 0; r < 4; ++r) acc[i][j][r] = 0.0f;

  const int arow = t >> 2;
  const int acol = (t & 3) * 16;

  for (int k0 = 0; k0 < K; k0 += 64) {
    { // stage A (row-major f32 -> hi/lo bf16)
      const float* src = A + (size_t)(row0 + arow) * K + k0 + acol;
      #pragma unroll
      for (int i = 0; i < 2; ++i) {
        const float4 f0 = *(const float4*)(src + i*8);
        const float4 f1 = *(const float4*)(src + i*8 + 4);
        ushort8 uh, ul;
        unsigned int p;
        p = split_bf(f0.x); uh[0]=(unsigned short)(p>>16); ul[0]=(unsigned short)p;
        p = split_bf(f0.y); uh[1]=(unsigned short)(p>>16); ul[1]=(unsigned short)p;
        p = split_bf(f0.z); uh[2]=(unsigned short)(p>>16); ul[2]=(unsigned short)p;
        p = split_bf(f0.w); uh[3]=(unsigned short)(p>>16); ul[3]=(unsigned short)p;
        p = split_bf(f1.x); uh[4]=(unsigned short)(p>>16); ul[4]=(unsigned short)p;
        p = split_bf(f1.y); uh[5]=(unsigned short)(p>>16); ul[5]=(unsigned short)p;
        p = split_bf(f1.z); uh[6]=(unsigned short)(p>>16); ul[6]=(unsigned short)p;
        p = split_bf(f1.w); uh[7]=(unsigned short)(p>>16); ul[7]=(unsigned short)p;
        *(ushort8*)&AsH[arow][acol + i*8] = uh;
        *(ushort8*)&AsL[arow][acol + i*8] = ul;
      }
    }
    if (TB) { // stage B from [N,K] rows, guard N
      const int gn = n0 + arow;
      if (gn < N) {
        const float* src = B + (size_t)gn * K + k0 + acol;
        #pragma unroll
        for (int i = 0; i < 2; ++i) {
          const float4 f0 = *(const float4*)(src + i*8);
          const float4 f1 = *(const float4*)(src + i*8 + 4);
          ushort8 uh, ul;
          unsigned int p;
          p = split_bf(f0.x); uh[0]=(unsigned short)(p>>16); ul[0]=(unsigned short)p;
          p = split_bf(f0.y); uh[1]=(unsigned short)(p>>16); ul[1]=(unsigned short)p;
          p = split_bf(f0.z); uh[2]=(unsigned short)(p>>16); ul[2]=(unsigned short)p;
          p = split_bf(f0.w); uh[3]=(unsigned short)(p>>16); ul[3]=(unsigned short)p;
          p = split_bf(f1.x); uh[4]=(unsigned short)(p>>16); ul[4]=(unsigned short)p;
          p = split_bf(f1.y); uh[5]=(unsigned short)(p>>16); ul[5]=(unsigned short)p;
          p = split_bf(f1.z); uh[6]=(unsigned short)(p>>16); ul[6]=(unsigned short)p;
          p = split_bf(f1.w); uh[7]=(unsigned short)(p>>16); ul[7]=(unsigned short)p;
          *(ushort8*)&BsH[arow][acol + i*8] = uh;
          *(ushort8*)&BsL[arow][acol + i*8] = ul;
        }
      } else {
        ushort8 z;
        #pragma unroll
        for (int j = 0; j < 8; ++j) z[j] = 0;
        *(ushort8*)&BsH[arow][acol]     = z;
        *(ushort8*)&BsH[arow][acol + 8] = z;
        *(ushort8*)&BsL[arow][acol]     = z;
        *(ushort8*)&BsL[arow][acol + 8] = z;
      }
    } else { // stage B from [K,N]: column reads (coalesced across lanes), store transposed
      const int bn  = t & 63;
      const int kk2 = (t >> 6) * 16;
      float tf[16];
      #pragma unroll
      for (int i = 0; i < 16; ++i)
        tf[i] = B[(size_t)(k0 + kk2 + i) * N + n0 + bn];
      #pragma unroll
      for (int i = 0; i < 2; ++i) {
        ushort8 uh, ul;
        #pragma unroll
        for (int j = 0; j < 8; ++j) {
          const unsigned int p = split_bf(tf[i*8 + j]);
          uh[j] = (unsigned short)(p >> 16);
          ul[j] = (unsigned short)p;
        }
        *(ushort8*)&BsH[bn][kk2 + i*8] = uh;
        *(ushort8*)&BsL[bn][kk2 + i*8] = ul;
      }
    }
    __syncthreads();
    #pragma unroll
    for (int kh = 0; kh < 2; ++kh) {
      bf16x8 ah[2], al[2], bh[2], bl[2];
      #pragma unroll
      for (int mt = 0; mt < 2; ++mt) {
        ah[mt] = *(const bf16x8*)&AsH[wm + mt*16 + fr][kh*32 + fg*8];
        al[mt] = *(const bf16x8*)&AsL[wm + mt*16 + fr][kh*32 + fg*8];
      }
      #pragma unroll
      for (int nt = 0; nt < 2; ++nt) {
        bh[nt] = *(const bf16x8*)&BsH[wn + nt*16 + fr][kh*32 + fg*8];
        bl[nt] = *(const bf16x8*)&BsL[wn + nt*16 + fr][kh*32 + fg*8];
      }
      #pragma unroll
      for (int mt = 0; mt < 2; ++mt)
        #pragma unroll
        for (int nt = 0; nt < 2; ++nt) {
          acc[mt][nt] = __builtin_amdgcn_mfma_f32_16x16x32_bf16(ah[mt], bh[nt], acc[mt][nt], 0, 0, 0);
          acc[mt][nt] = __builtin_amdgcn_mfma_f32_16x16x32_bf16(ah[mt], bl[nt], acc[mt][nt], 0, 0, 0);
          acc[mt][nt] = __builtin_amdgcn_mfma_f32_16x16x32_bf16(al[mt], bh[nt], acc[mt][nt], 0, 0, 0);
        }
    }
    __syncthreads();
  }

  // epilogue: C/D layout col=lane&15, row=(lane>>4)*4+reg  [guide §3, m89-verified]
  #pragma unroll
  for (int mt = 0; mt < 2; ++mt) {
    #pragma unroll
    for (int nt = 0; nt < 2; ++nt) {
      const int col = n0 + wn + nt*16 + fr;
      if (!TB || col < N) {
        const int rbase = row0 + wm + mt*16 + fg*4;
        const float bcol = BIAS ? bias[col] : 0.0f;
        #pragma unroll
        for (int r = 0; r < 4; ++r) {
          float val = acc[mt][nt][r];
          if (BIAS)  val += bcol;
          if (GELU_) val = gelu_f(val);
          const size_t off = (size_t)(rbase + r) * N + col;
          if (RES)   val += res[off];
          C[off] = val;
        }
      }
    }
  }
}

// ---------------- host-side orchestration ----------------
extern "C" void kernel_launch(void* const* d_in, const int* in_sizes, int n_in,
                              void* d_out, int out_size, void* d_ws, size_t ws_size,
                              hipStream_t stream)
{
  const int*   ids = (const int*)  d_in[0];
  const float* tok = (const float*)d_in[1];
  const float* ew  = (const float*)d_in[2];
  const float* eb  = (const float*)d_in[3];
  const float* wq  = (const float*)d_in[4];
  const float* wk  = (const float*)d_in[5];
  const float* wv  = (const float*)d_in[6];
  const float* wo  = (const float*)d_in[7];
  const float* n1w = (const float*)d_in[8];
  const float* n1b = (const float*)d_in[9];
  const float* n2w = (const float*)d_in[10];
  const float* n2b = (const float*)d_in[11];
  const float* m1w = (const float*)d_in[12];
  const float* m1b = (const float*)d_in[13];
  const float* m2w = (const float*)d_in[14];
  const float* m2b = (const float*)d_in[15];
  const float* onw = (const float*)d_in[16];
  const float* onb = (const float*)d_in[17];

  // scratch: x,h in ws (25.2 MB); g,q,k,v parked inside d_out (overwritten by logits last)
  float* x   = (float*)d_ws;
  float* h   = x + (size_t)Tt * Dm;
  float* out = (float*)d_out;
  float* g   = out;                       // 4096*3072 = 12.6M floats
  float* q   = out + (size_t)(1u << 24);  // 16.8M
  float* k   = q   + (size_t)(1u << 22);
  float* v   = k   + (size_t)(1u << 22);  // ends at 29.4M << 205.8M

  ln_kernel<<<Tt, 256, 0, stream>>>(tok, ids, ew, eb, x);

  for (int l = 0; l < Ll; ++l) {
    ln_kernel<<<Tt, 256, 0, stream>>>(x, nullptr, n1w + l*Dm, n1b + l*Dm, h);
    gemm_kernel<false,false,false,false><<<dim3(12,64), 256, 0, stream>>>(
        h, wq + (size_t)l*Dm*Dm, nullptr, nullptr, q, Tt, Dm, Dm);
    gemm_kernel<false,false,false,false><<<dim3(12,64), 256, 0, stream>>>(
        h, wk + (size_t)l*Dm*Dm, nullptr, nullptr, k, Tt, Dm, Dm);
    gemm_kernel<false,false,false,false><<<dim3(12,64), 256, 0, stream>>>(
        h, wv + (size_t)l*Dm*Dm, nullptr, nullptr, v, Tt, Dm, Dm);
    rope_kernel<<<6144, 256, 0, stream>>>(q, k);
    ttt_scan_kernel<<<48, 256, 0, stream>>>(q, k, v);     // O -> q
    gemm_kernel<false,false,false,true><<<dim3(12,64), 256, 0, stream>>>(
        q, wo + (size_t)l*Dm*Dm, nullptr, x, x, Tt, Dm, Dm);
    ln_kernel<<<Tt, 256, 0, stream>>>(x, nullptr, n2w + l*Dm, n2b + l*Dm, h);
    gemm_kernel<false,true,true,false><<<dim3(48,64), 256, 0, stream>>>(
        h, m1w + (size_t)l*Dm*Ff, m1b + (size_t)l*Ff, nullptr, g, Tt, Ff, Dm);
    gemm_kernel<false,true,false,true><<<dim3(12,64), 256, 0, stream>>>(
        g, m2w + (size_t)l*Ff*Dm, m2b + (size_t)l*Dm, x, x, Tt, Dm, Ff);
  }

  ln_kernel<<<Tt, 256, 0, stream>>>(x, nullptr, onw, onb, h);
  gemm_kernel<true,false,false,false><<<dim3((Vv+63)/64, 64), 256, 0, stream>>>(
      h, tok, nullptr, nullptr, out, Tt, Vv, Dm);
}

// Round 4
// 7679.975 us; speedup vs baseline: 1.7106x; 1.7106x over previous
//
#include <hip/hip_runtime.h>
#include <cstdint>
#include <cstddef>

#define Dm 768
#define Hh 12
#define DHd 64
#define Ll 12
#define Vv 50257
#define Tt 4096
#define Ff 3072
#define ETA (1.0f/16.0f)

typedef __attribute__((ext_vector_type(8))) short bf16x8;
typedef __attribute__((ext_vector_type(8))) unsigned short ushort8;
typedef __attribute__((ext_vector_type(4))) float f32x4;

static __device__ __forceinline__ unsigned short f2bf(float f){
  union { float f; unsigned int u; } v; v.f = f;
  unsigned int r = v.u + 0x7fffu + ((v.u >> 16) & 1u);
  return (unsigned short)(r >> 16);
}
// returns (hi<<16)|lo : hi=bf16(f), lo=bf16(f - hi)
static __device__ __forceinline__ unsigned int split_bf(float f){
  const unsigned short h = f2bf(f);
  union { unsigned int u; float f; } vh; vh.u = ((unsigned int)h) << 16;
  const unsigned short l = f2bf(f - vh.f);
  return (((unsigned int)h) << 16) | (unsigned int)l;
}

// ---------------- LayerNorm (optional embedding gather via ids) ----------------
__global__ __launch_bounds__(256)
void ln_kernel(const float* __restrict__ in, const int* __restrict__ ids,
               const float* __restrict__ w, const float* __restrict__ b,
               float* __restrict__ out)
{
  const int row = blockIdx.x;
  const int t = threadIdx.x;
  const float* px = in + (ids ? (size_t)ids[row] * Dm : (size_t)row * Dm);
  float x0 = px[t], x1 = px[t+256], x2 = px[t+512];
  float s  = x0 + x1 + x2;
  float s2 = x0*x0 + x1*x1 + x2*x2;
  #pragma unroll
  for (int o = 32; o > 0; o >>= 1) { s += __shfl_xor(s, o); s2 += __shfl_xor(s2, o); }
  __shared__ float ls[4], ls2[4];
  if ((t & 63) == 0) { ls[t>>6] = s; ls2[t>>6] = s2; }
  __syncthreads();
  s  = ls[0]+ls[1]+ls[2]+ls[3];
  s2 = ls2[0]+ls2[1]+ls2[2]+ls2[3];
  const float mu  = s * (1.0f/Dm);
  const float var = s2 * (1.0f/Dm) - mu*mu;
  const float rs  = rsqrtf(var + 1e-5f);
  float* po = out + (size_t)row * Dm;
  po[t]     = (x0-mu)*rs*w[t]     + b[t];
  po[t+256] = (x1-mu)*rs*w[t+256] + b[t+256];
  po[t+512] = (x2-mu)*rs*w[t+512] + b[t+512];
}

// ---------------- RoPE (in-place on q and k) ----------------
__global__ __launch_bounds__(256)
void rope_kernel(float* __restrict__ q, float* __restrict__ k)
{
  const int gid = blockIdx.x * 256 + threadIdx.x;
  if (gid >= Tt * Hh * 32) return;
  const int tkn = gid / (Hh * 32);
  const int r   = gid - tkn * (Hh * 32);
  const int hh  = r >> 5;
  const int d   = r & 31;
  const int s   = tkn & 1023;
  const float freq = 1.0f / powf(10000.0f, (float)d * (1.0f/32.0f));
  const float ang  = (float)s * freq;
  const float c = cosf(ang), sn = sinf(ang);
  const size_t base = (size_t)tkn * Dm + hh * DHd + d;
  float a1 = q[base], a2 = q[base + 32];
  q[base]      = a1*c - a2*sn;
  q[base + 32] = a1*sn + a2*c;
  float b1 = k[base], b2 = k[base + 32];
  k[base]      = b1*c - b2*sn;
  k[base + 32] = b1*sn + b2*c;
}

// ---------------- TTT chunked scan: 4-way e-split, block = (head, eslice) ----------------
// Each block owns 16 e-columns of W (64x16). A is recomputed redundantly per slice.
// O is written to ob (NOT in place: sibling slices still read q).
__global__ __launch_bounds__(256)
void ttt_scan_kernel(const float* __restrict__ qin, const float* __restrict__ kk,
                     const float* __restrict__ vv, float* __restrict__ ob)
{
  const int head = blockIdx.x >> 2;   // 0..47
  const int es   = blockIdx.x & 3;    // e-slice 0..3
  const int b  = head / Hh;
  const int hd = head % Hh;
  const int t  = threadIdx.x;
  __shared__ float Wm[64][17];        // W[d][e_local], padded (write pattern)
  __shared__ float kms[16][68];
  __shared__ float qms[16][68];
  __shared__ float Es[16][16];
  __shared__ float Asc[16][16];

  const int e   = t & 15;             // e_local / n index
  const int m16 = t >> 4;             // m / d-group index
  const int sr  = t >> 4;             // staging row
  const int sc  = (t & 15) * 4;       // staging col

  for (int i = t; i < 64*17; i += 256) ((float*)Wm)[i] = 0.0f;

  const int tb0 = b * 1024;
  const size_t gbase = (size_t)hd * DHd;
  // prefetch chunk 0
  float4 kr = *(const float4*)&kk [(size_t)(tb0+sr)*Dm + gbase + sc];
  float4 qr = *(const float4*)&qin[(size_t)(tb0+sr)*Dm + gbase + sc];
  __syncthreads();

  for (int c = 0; c < 64; ++c) {
    const int tb = tb0 + c*16;
    *(float4*)&kms[sr][sc] = kr;
    *(float4*)&qms[sr][sc] = qr;
    __syncthreads();
    if (c < 63) {  // prefetch next chunk (hidden under compute)
      kr = *(const float4*)&kk [(size_t)(tb+16+sr)*Dm + gbase + sc];
      qr = *(const float4*)&qin[(size_t)(tb+16+sr)*Dm + gbase + sc];
    }
    const float vreg = vv[(size_t)(tb+m16)*Dm + gbase + es*16 + e];
    // E[m][e] = (km@W)[m][e] - v ; Oq = (qm@W)[m][e] ; one output per thread
    float aE = -vreg, aO = 0.0f;
    #pragma unroll
    for (int d = 0; d < 64; ++d) {
      const float w_ = Wm[d][e];
      aE += kms[m16][d] * w_;
      aO += qms[m16][d] * w_;
    }
    // A[m][n] (redundant across slices): thread (m16, e)
    float aA = 0.0f;
    #pragma unroll
    for (int d = 0; d < 64; ++d) aA += qms[m16][d] * kms[e][d];
    Es[m16][e]  = aE;
    Asc[m16][e] = (e <= m16) ? (-ETA * aA) : 0.0f;
    __syncthreads();
    // O = Oq + Asc@E
    float acc = aO;
    #pragma unroll
    for (int n = 0; n < 16; ++n) acc += Asc[m16][n] * Es[n][e];
    ob[(size_t)(tb+m16)*Dm + gbase + es*16 + e] = acc;
    // W[d][e] -= eta * (km^T @ E)[d][e], thread owns 4 d's
    #pragma unroll
    for (int j = 0; j < 4; ++j) {
      const int d = m16*4 + j;
      float a = 0.0f;
      #pragma unroll
      for (int m = 0; m < 16; ++m) a += kms[m][d] * Es[m][e];
      Wm[d][e] -= ETA * a;
    }
    __syncthreads();
  }
}

// ---------------- split-bf16 MFMA GEMM, 64x64x64 tile, XOR-swizzled LDS ----------------
// TERMS=3: acc = hi*hi + hi*lo + lo*hi (~fp32). TERMS=1: plain bf16.
// byte ^= (row&7)<<4 swizzle on both write and read (T2; conflict-free for b128).
static __device__ __forceinline__ float gelu_f(float x){
  const float u = 0.7978845608028654f * (x + 0.044715f * x*x*x);
  return 0.5f * x * (1.0f + tanhf(u));
}

template<int TERMS, bool TB, bool BIAS, bool GELU_, bool RES>
__global__ __launch_bounds__(256)
void gemm_kernel(const float* __restrict__ A, const float* __restrict__ B,
                 const float* __restrict__ bias, const float* __restrict__ res,
                 float* __restrict__ C, int M, int N, int K)
{
  constexpr int NB = (TERMS == 3) ? 2 : 1;
  __shared__ __attribute__((aligned(16))) unsigned short As[NB][64][64];
  __shared__ __attribute__((aligned(16))) unsigned short Bs[NB][64][64];
  const int t    = threadIdx.x;
  const int lane = t & 63;
  const int fr   = lane & 15;
  const int fg   = lane >> 4;
  const int wave = t >> 6;
  const int wm   = (wave >> 1) * 32;
  const int wn   = (wave & 1) * 32;
  const int row0 = blockIdx.y * 64;
  const int n0   = blockIdx.x * 64;

  f32x4 acc[2][2];
  #pragma unroll
  for (int i = 0; i < 2; ++i)
    #pragma unroll
    for (int j = 0; j < 2; ++j)
      #pragma unroll
      for (int r = 0; r < 4; ++r) acc[i][j][r] = 0.0f;

  const int arow = t >> 2;
  const int acol = (t & 3) * 16;

  for (int k0 = 0; k0 < K; k0 += 64) {
    { // stage A
      const float* src = A + (size_t)(row0 + arow) * K + k0 + acol;
      #pragma unroll
      for (int i = 0; i < 2; ++i) {
        const float4 f0 = *(const float4*)(src + i*8);
        const float4 f1 = *(const float4*)(src + i*8 + 4);
        ushort8 uh, ul;
        unsigned int p;
        p=split_bf(f0.x); uh[0]=(unsigned short)(p>>16); ul[0]=(unsigned short)p;
        p=split_bf(f0.y); uh[1]=(unsigned short)(p>>16); ul[1]=(unsigned short)p;
        p=split_bf(f0.z); uh[2]=(unsigned short)(p>>16); ul[2]=(unsigned short)p;
        p=split_bf(f0.w); uh[3]=(unsigned short)(p>>16); ul[3]=(unsigned short)p;
        p=split_bf(f1.x); uh[4]=(unsigned short)(p>>16); ul[4]=(unsigned short)p;
        p=split_bf(f1.y); uh[5]=(unsigned short)(p>>16); ul[5]=(unsigned short)p;
        p=split_bf(f1.z); uh[6]=(unsigned short)(p>>16); ul[6]=(unsigned short)p;
        p=split_bf(f1.w); uh[7]=(unsigned short)(p>>16); ul[7]=(unsigned short)p;
        const int byt = (arow*128 + acol*2 + i*16) ^ ((arow & 7) << 4);
        *(ushort8*)((char*)As[0] + byt) = uh;
        if (TERMS == 3) *(ushort8*)((char*)As[1] + byt) = ul;
      }
    }
    if (TB) { // stage B from [N,K] rows, guard N
      const int gn = n0 + arow;
      if (gn < N) {
        const float* src = B + (size_t)gn * K + k0 + acol;
        #pragma unroll
        for (int i = 0; i < 2; ++i) {
          const float4 f0 = *(const float4*)(src + i*8);
          const float4 f1 = *(const float4*)(src + i*8 + 4);
          ushort8 uh, ul;
          unsigned int p;
          p=split_bf(f0.x); uh[0]=(unsigned short)(p>>16); ul[0]=(unsigned short)p;
          p=split_bf(f0.y); uh[1]=(unsigned short)(p>>16); ul[1]=(unsigned short)p;
          p=split_bf(f0.z); uh[2]=(unsigned short)(p>>16); ul[2]=(unsigned short)p;
          p=split_bf(f0.w); uh[3]=(unsigned short)(p>>16); ul[3]=(unsigned short)p;
          p=split_bf(f1.x); uh[4]=(unsigned short)(p>>16); ul[4]=(unsigned short)p;
          p=split_bf(f1.y); uh[5]=(unsigned short)(p>>16); ul[5]=(unsigned short)p;
          p=split_bf(f1.z); uh[6]=(unsigned short)(p>>16); ul[6]=(unsigned short)p;
          p=split_bf(f1.w); uh[7]=(unsigned short)(p>>16); ul[7]=(unsigned short)p;
          const int byt = (arow*128 + acol*2 + i*16) ^ ((arow & 7) << 4);
          *(ushort8*)((char*)Bs[0] + byt) = uh;
          if (TERMS == 3) *(ushort8*)((char*)Bs[1] + byt) = ul;
        }
      } else {
        ushort8 z;
        #pragma unroll
        for (int j = 0; j < 8; ++j) z[j] = 0;
        #pragma unroll
        for (int i = 0; i < 2; ++i) {
          const int byt = (arow*128 + acol*2 + i*16) ^ ((arow & 7) << 4);
          *(ushort8*)((char*)Bs[0] + byt) = z;
          if (TERMS == 3) *(ushort8*)((char*)Bs[1] + byt) = z;
        }
      }
    } else { // stage B from [K,N]: column reads, store transposed
      const int bn  = t & 63;
      const int kk2 = (t >> 6) * 16;
      float tf[16];
      #pragma unroll
      for (int i = 0; i < 16; ++i)
        tf[i] = B[(size_t)(k0 + kk2 + i) * N + n0 + bn];
      #pragma unroll
      for (int i = 0; i < 2; ++i) {
        ushort8 uh, ul;
        #pragma unroll
        for (int j = 0; j < 8; ++j) {
          const unsigned int p = split_bf(tf[i*8 + j]);
          uh[j] = (unsigned short)(p >> 16);
          ul[j] = (unsigned short)p;
        }
        const int byt = (bn*128 + kk2*2 + i*16) ^ ((bn & 7) << 4);
        *(ushort8*)((char*)Bs[0] + byt) = uh;
        if (TERMS == 3) *(ushort8*)((char*)Bs[1] + byt) = ul;
      }
    }
    __syncthreads();
    #pragma unroll
    for (int kh = 0; kh < 2; ++kh) {
      bf16x8 ah[2], al[2], bh[2], bl[2];
      const int swz = (fr & 7) << 4;
      #pragma unroll
      for (int mt = 0; mt < 2; ++mt) {
        const int byt = ((wm + mt*16 + fr)*128 + kh*64 + fg*16) ^ swz;
        ah[mt] = *(const bf16x8*)((const char*)As[0] + byt);
        if (TERMS == 3) al[mt] = *(const bf16x8*)((const char*)As[1] + byt);
      }
      #pragma unroll
      for (int nt = 0; nt < 2; ++nt) {
        const int byt = ((wn + nt*16 + fr)*128 + kh*64 + fg*16) ^ swz;
        bh[nt] = *(const bf16x8*)((const char*)Bs[0] + byt);
        if (TERMS == 3) bl[nt] = *(const bf16x8*)((const char*)Bs[1] + byt);
      }
      #pragma unroll
      for (int mt = 0; mt < 2; ++mt)
        #pragma unroll
        for (int nt = 0; nt < 2; ++nt) {
          acc[mt][nt] = __builtin_amdgcn_mfma_f32_16x16x32_bf16(ah[mt], bh[nt], acc[mt][nt], 0, 0, 0);
          if (TERMS == 3) {
            acc[mt][nt] = __builtin_amdgcn_mfma_f32_16x16x32_bf16(ah[mt], bl[nt], acc[mt][nt], 0, 0, 0);
            acc[mt][nt] = __builtin_amdgcn_mfma_f32_16x16x32_bf16(al[mt], bh[nt], acc[mt][nt], 0, 0, 0);
          }
        }
    }
    __syncthreads();
  }

  // epilogue: C/D layout col=lane&15, row=(lane>>4)*4+reg
  #pragma unroll
  for (int mt = 0; mt < 2; ++mt) {
    #pragma unroll
    for (int nt = 0; nt < 2; ++nt) {
      const int col = n0 + wn + nt*16 + fr;
      if (!TB || col < N) {
        const int rbase = row0 + wm + mt*16 + fg*4;
        const float bcol = BIAS ? bias[col] : 0.0f;
        #pragma unroll
        for (int r = 0; r < 4; ++r) {
          float val = acc[mt][nt][r];
          if (BIAS)  val += bcol;
          if (GELU_) val = gelu_f(val);
          const size_t off = (size_t)(rbase + r) * N + col;
          if (RES)   val += res[off];
          C[off] = val;
        }
      }
    }
  }
}

// ---------------- logits GEMM: persistent-N, plain bf16, C = A @ B^T ----------------
// A[4096][768] (h), B[50257][768] (tok_emb), C[4096][50257].
// Grid (786, 4): block owns 64 cols, loops 16 m-tiles; B panel stays in L2.
__global__ __launch_bounds__(256)
void logits_kernel(const float* __restrict__ A, const float* __restrict__ B,
                   float* __restrict__ C)
{
  __shared__ __attribute__((aligned(16))) unsigned short As[64][64];
  __shared__ __attribute__((aligned(16))) unsigned short Bs[64][64];
  const int t    = threadIdx.x;
  const int lane = t & 63;
  const int fr   = lane & 15;
  const int fg   = lane >> 4;
  const int wave = t >> 6;
  const int wm   = (wave >> 1) * 32;
  const int wn   = (wave & 1) * 32;
  const int n0   = blockIdx.x * 64;
  const int arow = t >> 2;
  const int acol = (t & 3) * 16;
  const int gn   = n0 + arow;

  for (int mt = 0; mt < 16; ++mt) {
    const int row0 = blockIdx.y * 1024 + mt * 64;
    f32x4 acc[2][2];
    #pragma unroll
    for (int i = 0; i < 2; ++i)
      #pragma unroll
      for (int j = 0; j < 2; ++j)
        #pragma unroll
        for (int r = 0; r < 4; ++r) acc[i][j][r] = 0.0f;

    for (int k0 = 0; k0 < Dm; k0 += 64) {
      { // A stage (hi only)
        const float* src = A + (size_t)(row0 + arow) * Dm + k0 + acol;
        #pragma unroll
        for (int i = 0; i < 2; ++i) {
          const float4 f0 = *(const float4*)(src + i*8);
          const float4 f1 = *(const float4*)(src + i*8 + 4);
          ushort8 u;
          u[0]=f2bf(f0.x); u[1]=f2bf(f0.y); u[2]=f2bf(f0.z); u[3]=f2bf(f0.w);
          u[4]=f2bf(f1.x); u[5]=f2bf(f1.y); u[6]=f2bf(f1.z); u[7]=f2bf(f1.w);
          const int byt = (arow*128 + acol*2 + i*16) ^ ((arow & 7) << 4);
          *(ushort8*)((char*)As + byt) = u;
        }
      }
      { // B stage from rows of tok_emb (TB), guard
        if (gn < Vv) {
          const float* src = B + (size_t)gn * Dm + k0 + acol;
          #pragma unroll
          for (int i = 0; i < 2; ++i) {
            const float4 f0 = *(const float4*)(src + i*8);
            const float4 f1 = *(const float4*)(src + i*8 + 4);
            ushort8 u;
            u[0]=f2bf(f0.x); u[1]=f2bf(f0.y); u[2]=f2bf(f0.z); u[3]=f2bf(f0.w);
            u[4]=f2bf(f1.x); u[5]=f2bf(f1.y); u[6]=f2bf(f1.z); u[7]=f2bf(f1.w);
            const int byt = (arow*128 + acol*2 + i*16) ^ ((arow & 7) << 4);
            *(ushort8*)((char*)Bs + byt) = u;
          }
        } else {
          ushort8 z;
          #pragma unroll
          for (int j = 0; j < 8; ++j) z[j] = 0;
          #pragma unroll
          for (int i = 0; i < 2; ++i) {
            const int byt = (arow*128 + acol*2 + i*16) ^ ((arow & 7) << 4);
            *(ushort8*)((char*)Bs + byt) = z;
          }
        }
      }
      __syncthreads();
      #pragma unroll
      for (int kh = 0; kh < 2; ++kh) {
        bf16x8 af[2], bf_[2];
        const int swz = (fr & 7) << 4;
        #pragma unroll
        for (int m2 = 0; m2 < 2; ++m2)
          af[m2] = *(const bf16x8*)((const char*)As + (((wm + m2*16 + fr)*128 + kh*64 + fg*16) ^ swz));
        #pragma unroll
        for (int n2 = 0; n2 < 2; ++n2)
          bf_[n2] = *(const bf16x8*)((const char*)Bs + (((wn + n2*16 + fr)*128 + kh*64 + fg*16) ^ swz));
        #pragma unroll
        for (int m2 = 0; m2 < 2; ++m2)
          #pragma unroll
          for (int n2 = 0; n2 < 2; ++n2)
            acc[m2][n2] = __builtin_amdgcn_mfma_f32_16x16x32_bf16(af[m2], bf_[n2], acc[m2][n2], 0, 0, 0);
      }
      __syncthreads();
    }

    #pragma unroll
    for (int m2 = 0; m2 < 2; ++m2) {
      #pragma unroll
      for (int n2 = 0; n2 < 2; ++n2) {
        const int col = n0 + wn + n2*16 + fr;
        if (col < Vv) {
          const int rbase = row0 + wm + m2*16 + fg*4;
          #pragma unroll
          for (int r = 0; r < 4; ++r)
            C[(size_t)(rbase + r) * Vv + col] = acc[m2][n2][r];
        }
      }
    }
  }
}

// ---------------- host-side orchestration ----------------
extern "C" void kernel_launch(void* const* d_in, const int* in_sizes, int n_in,
                              void* d_out, int out_size, void* d_ws, size_t ws_size,
                              hipStream_t stream)
{
  const int*   ids = (const int*)  d_in[0];
  const float* tok = (const float*)d_in[1];
  const float* ew  = (const float*)d_in[2];
  const float* eb  = (const float*)d_in[3];
  const float* wq  = (const float*)d_in[4];
  const float* wk  = (const float*)d_in[5];
  const float* wv  = (const float*)d_in[6];
  const float* wo  = (const float*)d_in[7];
  const float* n1w = (const float*)d_in[8];
  const float* n1b = (const float*)d_in[9];
  const float* n2w = (const float*)d_in[10];
  const float* n2b = (const float*)d_in[11];
  const float* m1w = (const float*)d_in[12];
  const float* m1b = (const float*)d_in[13];
  const float* m2w = (const float*)d_in[14];
  const float* m2b = (const float*)d_in[15];
  const float* onw = (const float*)d_in[16];
  const float* onb = (const float*)d_in[17];

  // scratch: x,h in ws; g,q,k,v,o parked inside d_out (overwritten by logits last)
  float* x   = (float*)d_ws;
  float* h   = x + (size_t)Tt * Dm;
  float* out = (float*)d_out;
  float* g   = out;                       // 12.6M floats
  float* q   = out + (size_t)(1u << 24);  // 16.8M
  float* k   = q   + (size_t)(1u << 22);
  float* v   = k   + (size_t)(1u << 22);
  float* ob  = v   + (size_t)(1u << 22);  // ends ~37.7M << 205.8M

  ln_kernel<<<Tt, 256, 0, stream>>>(tok, ids, ew, eb, x);

  for (int l = 0; l < Ll; ++l) {
    ln_kernel<<<Tt, 256, 0, stream>>>(x, nullptr, n1w + l*Dm, n1b + l*Dm, h);
    gemm_kernel<3,false,false,false,false><<<dim3(12,64), 256, 0, stream>>>(
        h, wq + (size_t)l*Dm*Dm, nullptr, nullptr, q, Tt, Dm, Dm);
    gemm_kernel<3,false,false,false,false><<<dim3(12,64), 256, 0, stream>>>(
        h, wk + (size_t)l*Dm*Dm, nullptr, nullptr, k, Tt, Dm, Dm);
    gemm_kernel<3,false,false,false,false><<<dim3(12,64), 256, 0, stream>>>(
        h, wv + (size_t)l*Dm*Dm, nullptr, nullptr, v, Tt, Dm, Dm);
    rope_kernel<<<6144, 256, 0, stream>>>(q, k);
    ttt_scan_kernel<<<192, 256, 0, stream>>>(q, k, v, ob);
    gemm_kernel<3,false,false,false,true><<<dim3(12,64), 256, 0, stream>>>(
        ob, wo + (size_t)l*Dm*Dm, nullptr, x, x, Tt, Dm, Dm);
    ln_kernel<<<Tt, 256, 0, stream>>>(x, nullptr, n2w + l*Dm, n2b + l*Dm, h);
    gemm_kernel<3,false,true,true,false><<<dim3(48,64), 256, 0, stream>>>(
        h, m1w + (size_t)l*Dm*Ff, m1b + (size_t)l*Ff, nullptr, g, Tt, Ff, Dm);
    gemm_kernel<3,false,true,false,true><<<dim3(12,64), 256, 0, stream>>>(
        g, m2w + (size_t)l*Ff*Dm, m2b + (size_t)l*Dm, x, x, Tt, Dm, Ff);
  }

  ln_kernel<<<Tt, 256, 0, stream>>>(x, nullptr, onw, onb, h);
  logits_kernel<<<dim3(786, 4), 256, 0, stream>>>(h, tok, out);
}

// Round 5
// 6139.299 us; speedup vs baseline: 2.1399x; 1.2510x over previous
//
#include <hip/hip_runtime.h>
#include <cstdint>
#include <cstddef>

#define Dm 768
#define Hh 12
#define DHd 64
#define Ll 12
#define Vv 50257
#define Tt 4096
#define Ff 3072
#define ETA (1.0f/16.0f)

typedef __attribute__((ext_vector_type(8))) short bf16x8;
typedef __attribute__((ext_vector_type(8))) unsigned short ushort8;
typedef __attribute__((ext_vector_type(4))) float f32x4;

static __device__ __forceinline__ unsigned short f2bf(float f){
  union { float f; unsigned int u; } v; v.f = f;
  unsigned int r = v.u + 0x7fffu + ((v.u >> 16) & 1u);
  return (unsigned short)(r >> 16);
}
// returns (hi<<16)|lo : hi=bf16(f), lo=bf16(f - hi)
static __device__ __forceinline__ uint32_t split_bf(float f){
  const unsigned short h = f2bf(f);
  union { uint32_t u; float f; } vh; vh.u = ((uint32_t)h) << 16;
  const unsigned short l = f2bf(f - vh.f);
  return (((uint32_t)h) << 16) | (uint32_t)l;
}

// ---------------- weight pre-split: f32 -> packed (hi|lo) u32 ----------------
__global__ __launch_bounds__(256)
void convw_kernel(const float* __restrict__ src, uint32_t* __restrict__ dst, int n4)
{
  for (int i = blockIdx.x*256 + threadIdx.x; i < n4; i += gridDim.x*256) {
    const float4 f = ((const float4*)src)[i];
    uint4 o;
    o.x = split_bf(f.x); o.y = split_bf(f.y); o.z = split_bf(f.z); o.w = split_bf(f.w);
    ((uint4*)dst)[i] = o;
  }
}

// ---------------- LayerNorm; OMODE: 0=f32, 1=packed u32, 2=bf16 ushort ----------------
template<int OMODE>
__global__ __launch_bounds__(256)
void ln_kernel(const float* __restrict__ in, const int* __restrict__ ids,
               const float* __restrict__ w, const float* __restrict__ b,
               void* __restrict__ outp)
{
  const int row = blockIdx.x;
  const int t = threadIdx.x;
  const float* px = in + (ids ? (size_t)ids[row] * Dm : (size_t)row * Dm);
  float x0 = px[t], x1 = px[t+256], x2 = px[t+512];
  float s  = x0 + x1 + x2;
  float s2 = x0*x0 + x1*x1 + x2*x2;
  #pragma unroll
  for (int o = 32; o > 0; o >>= 1) { s += __shfl_xor(s, o); s2 += __shfl_xor(s2, o); }
  __shared__ float ls[4], ls2[4];
  if ((t & 63) == 0) { ls[t>>6] = s; ls2[t>>6] = s2; }
  __syncthreads();
  s  = ls[0]+ls[1]+ls[2]+ls[3];
  s2 = ls2[0]+ls2[1]+ls2[2]+ls2[3];
  const float mu  = s * (1.0f/Dm);
  const float var = s2 * (1.0f/Dm) - mu*mu;
  const float rs  = rsqrtf(var + 1e-5f);
  const float v0 = (x0-mu)*rs*w[t]     + b[t];
  const float v1 = (x1-mu)*rs*w[t+256] + b[t+256];
  const float v2 = (x2-mu)*rs*w[t+512] + b[t+512];
  if (OMODE == 0) {
    float* po = (float*)outp + (size_t)row * Dm;
    po[t] = v0; po[t+256] = v1; po[t+512] = v2;
  } else if (OMODE == 1) {
    uint32_t* po = (uint32_t*)outp + (size_t)row * Dm;
    po[t] = split_bf(v0); po[t+256] = split_bf(v1); po[t+512] = split_bf(v2);
  } else {
    unsigned short* po = (unsigned short*)outp + (size_t)row * Dm;
    po[t] = f2bf(v0); po[t+256] = f2bf(v1); po[t+512] = f2bf(v2);
  }
}

// ---------------- RoPE (in-place on q and k) ----------------
__global__ __launch_bounds__(256)
void rope_kernel(float* __restrict__ q, float* __restrict__ k)
{
  const int gid = blockIdx.x * 256 + threadIdx.x;
  if (gid >= Tt * Hh * 32) return;
  const int tkn = gid / (Hh * 32);
  const int r   = gid - tkn * (Hh * 32);
  const int hh  = r >> 5;
  const int d   = r & 31;
  const int s   = tkn & 1023;
  const float freq = 1.0f / powf(10000.0f, (float)d * (1.0f/32.0f));
  const float ang  = (float)s * freq;
  const float c = cosf(ang), sn = sinf(ang);
  const size_t base = (size_t)tkn * Dm + hh * DHd + d;
  float a1 = q[base], a2 = q[base + 32];
  q[base]      = a1*c - a2*sn;
  q[base + 32] = a1*sn + a2*c;
  float b1 = k[base], b2 = k[base + 32];
  k[base]      = b1*c - b2*sn;
  k[base + 32] = b1*sn + b2*c;
}

// ---------------- TTT chunked scan: 4-way e-split; O written packed ----------------
__global__ __launch_bounds__(256)
void ttt_scan_kernel(const float* __restrict__ qin, const float* __restrict__ kk,
                     const float* __restrict__ vv, uint32_t* __restrict__ ob)
{
  const int head = blockIdx.x >> 2;
  const int es   = blockIdx.x & 3;
  const int b  = head / Hh;
  const int hd = head % Hh;
  const int t  = threadIdx.x;
  __shared__ float Wm[64][17];
  __shared__ float kms[16][68];
  __shared__ float qms[16][68];
  __shared__ float Es[16][16];
  __shared__ float Asc[16][16];

  const int e   = t & 15;
  const int m16 = t >> 4;
  const int sr  = t >> 4;
  const int sc  = (t & 15) * 4;

  for (int i = t; i < 64*17; i += 256) ((float*)Wm)[i] = 0.0f;

  const int tb0 = b * 1024;
  const size_t gbase = (size_t)hd * DHd;
  float4 kr = *(const float4*)&kk [(size_t)(tb0+sr)*Dm + gbase + sc];
  float4 qr = *(const float4*)&qin[(size_t)(tb0+sr)*Dm + gbase + sc];
  __syncthreads();

  for (int c = 0; c < 64; ++c) {
    const int tb = tb0 + c*16;
    *(float4*)&kms[sr][sc] = kr;
    *(float4*)&qms[sr][sc] = qr;
    __syncthreads();
    if (c < 63) {
      kr = *(const float4*)&kk [(size_t)(tb+16+sr)*Dm + gbase + sc];
      qr = *(const float4*)&qin[(size_t)(tb+16+sr)*Dm + gbase + sc];
    }
    const float vreg = vv[(size_t)(tb+m16)*Dm + gbase + es*16 + e];
    float aE = -vreg, aO = 0.0f;
    #pragma unroll
    for (int d = 0; d < 64; ++d) {
      const float w_ = Wm[d][e];
      aE += kms[m16][d] * w_;
      aO += qms[m16][d] * w_;
    }
    float aA = 0.0f;
    #pragma unroll
    for (int d = 0; d < 64; ++d) aA += qms[m16][d] * kms[e][d];
    Es[m16][e]  = aE;
    Asc[m16][e] = (e <= m16) ? (-ETA * aA) : 0.0f;
    __syncthreads();
    float acc = aO;
    #pragma unroll
    for (int n = 0; n < 16; ++n) acc += Asc[m16][n] * Es[n][e];
    ob[(size_t)(tb+m16)*Dm + gbase + es*16 + e] = split_bf(acc);
    #pragma unroll
    for (int j = 0; j < 4; ++j) {
      const int d = m16*4 + j;
      float a = 0.0f;
      #pragma unroll
      for (int m = 0; m < 16; ++m) a += kms[m][d] * Es[m][e];
      Wm[d][e] -= ETA * a;
    }
    __syncthreads();
  }
}

// ---------------- split-bf16 MFMA GEMM on PACKED operands ----------------
// A[M,K], B[K,N] both packed u32 (hi|lo). acc = hi*hi + hi*lo + lo*hi.
static __device__ __forceinline__ float gelu_f(float x){
  const float u = 0.7978845608028654f * (x + 0.044715f * x*x*x);
  return 0.5f * x * (1.0f + tanhf(u));
}

template<bool BIAS, bool GELU_, bool RES, bool PACKOUT>
__global__ __launch_bounds__(256)
void gemm_kernel(const uint32_t* __restrict__ A, const uint32_t* __restrict__ B,
                 const float* __restrict__ bias, const float* __restrict__ res,
                 void* __restrict__ Cp, int M, int N, int K)
{
  __shared__ __attribute__((aligned(16))) unsigned short AsH[64][64];
  __shared__ __attribute__((aligned(16))) unsigned short AsL[64][64];
  __shared__ __attribute__((aligned(16))) unsigned short BsH[64][64];
  __shared__ __attribute__((aligned(16))) unsigned short BsL[64][64];
  const int t    = threadIdx.x;
  const int lane = t & 63;
  const int fr   = lane & 15;
  const int fg   = lane >> 4;
  const int wave = t >> 6;
  const int wm   = (wave >> 1) * 32;
  const int wn   = (wave & 1) * 32;
  const int row0 = blockIdx.y * 64;
  const int n0   = blockIdx.x * 64;

  f32x4 acc[2][2];
  #pragma unroll
  for (int i = 0; i < 2; ++i)
    #pragma unroll
    for (int j = 0; j < 2; ++j)
      #pragma unroll
      for (int r = 0; r < 4; ++r) acc[i][j][r] = 0.0f;

  const int arow = t >> 2;
  const int acol = (t & 3) * 16;
  const int bn   = t & 63;
  const int kk2  = (t >> 6) * 16;

  for (int k0 = 0; k0 < K; k0 += 64) {
    { // stage A (packed -> hi/lo)
      const uint32_t* src = A + (size_t)(row0 + arow) * K + k0 + acol;
      #pragma unroll
      for (int i = 0; i < 2; ++i) {
        const uint4 p0 = *(const uint4*)(src + i*8);
        const uint4 p1 = *(const uint4*)(src + i*8 + 4);
        ushort8 uh, ul;
        uh[0]=(unsigned short)(p0.x>>16); ul[0]=(unsigned short)p0.x;
        uh[1]=(unsigned short)(p0.y>>16); ul[1]=(unsigned short)p0.y;
        uh[2]=(unsigned short)(p0.z>>16); ul[2]=(unsigned short)p0.z;
        uh[3]=(unsigned short)(p0.w>>16); ul[3]=(unsigned short)p0.w;
        uh[4]=(unsigned short)(p1.x>>16); ul[4]=(unsigned short)p1.x;
        uh[5]=(unsigned short)(p1.y>>16); ul[5]=(unsigned short)p1.y;
        uh[6]=(unsigned short)(p1.z>>16); ul[6]=(unsigned short)p1.z;
        uh[7]=(unsigned short)(p1.w>>16); ul[7]=(unsigned short)p1.w;
        const int byt = (arow*128 + acol*2 + i*16) ^ ((arow & 7) << 4);
        *(ushort8*)((char*)AsH + byt) = uh;
        *(ushort8*)((char*)AsL + byt) = ul;
      }
    }
    { // stage B (packed column reads)
      uint32_t tp[16];
      #pragma unroll
      for (int i = 0; i < 16; ++i)
        tp[i] = B[(size_t)(k0 + kk2 + i) * N + n0 + bn];
      #pragma unroll
      for (int i = 0; i < 2; ++i) {
        ushort8 uh, ul;
        #pragma unroll
        for (int j = 0; j < 8; ++j) {
          const uint32_t p = tp[i*8 + j];
          uh[j] = (unsigned short)(p >> 16);
          ul[j] = (unsigned short)p;
        }
        const int byt = (bn*128 + kk2*2 + i*16) ^ ((bn & 7) << 4);
        *(ushort8*)((char*)BsH + byt) = uh;
        *(ushort8*)((char*)BsL + byt) = ul;
      }
    }
    __syncthreads();
    #pragma unroll
    for (int kh = 0; kh < 2; ++kh) {
      bf16x8 ah[2], al[2], bh[2], bl[2];
      const int swz = (fr & 7) << 4;
      #pragma unroll
      for (int mt = 0; mt < 2; ++mt) {
        const int byt = ((wm + mt*16 + fr)*128 + kh*64 + fg*16) ^ swz;
        ah[mt] = *(const bf16x8*)((const char*)AsH + byt);
        al[mt] = *(const bf16x8*)((const char*)AsL + byt);
      }
      #pragma unroll
      for (int nt = 0; nt < 2; ++nt) {
        const int byt = ((wn + nt*16 + fr)*128 + kh*64 + fg*16) ^ swz;
        bh[nt] = *(const bf16x8*)((const char*)BsH + byt);
        bl[nt] = *(const bf16x8*)((const char*)BsL + byt);
      }
      #pragma unroll
      for (int mt = 0; mt < 2; ++mt)
        #pragma unroll
        for (int nt = 0; nt < 2; ++nt) {
          acc[mt][nt] = __builtin_amdgcn_mfma_f32_16x16x32_bf16(ah[mt], bh[nt], acc[mt][nt], 0, 0, 0);
          acc[mt][nt] = __builtin_amdgcn_mfma_f32_16x16x32_bf16(ah[mt], bl[nt], acc[mt][nt], 0, 0, 0);
          acc[mt][nt] = __builtin_amdgcn_mfma_f32_16x16x32_bf16(al[mt], bh[nt], acc[mt][nt], 0, 0, 0);
        }
    }
    __syncthreads();
  }

  #pragma unroll
  for (int mt = 0; mt < 2; ++mt) {
    #pragma unroll
    for (int nt = 0; nt < 2; ++nt) {
      const int col = n0 + wn + nt*16 + fr;
      const int rbase = row0 + wm + mt*16 + fg*4;
      const float bcol = BIAS ? bias[col] : 0.0f;
      #pragma unroll
      for (int r = 0; r < 4; ++r) {
        float val = acc[mt][nt][r];
        if (BIAS)  val += bcol;
        if (GELU_) val = gelu_f(val);
        const size_t off = (size_t)(rbase + r) * N + col;
        if (PACKOUT) {
          ((uint32_t*)Cp)[off] = split_bf(val);
        } else {
          if (RES) val += res[off];
          ((float*)Cp)[off] = val;
        }
      }
    }
  }
}

// ---------------- logits GEMM: B-panel resident in LDS ----------------
// A = hbf[4096][768] bf16, B = tok_emb[50257][768] f32 (converted on load).
// Grid (786, 2), 512 threads. Block: 64 vocab cols, loops 8 m-tiles of 256 rows.
// Wave tile 32m x 64n. C = A @ B^T, f32.
__global__ __launch_bounds__(512)
void logits_kernel(const unsigned short* __restrict__ hbf, const float* __restrict__ tok,
                   float* __restrict__ C)
{
  __shared__ unsigned short Bp[64][776];                       // 97 KB, +8 pad
  __shared__ __attribute__((aligned(16))) unsigned short As[256][64];  // 32 KB
  const int t  = threadIdx.x;
  const int n0 = blockIdx.x * 64;

  // fill B panel once: 64 rows x 768 (f32 -> bf16)
  for (int idx = t; idx < 64*96; idx += 512) {
    const int r  = idx / 96;
    const int c8 = (idx - r*96) * 8;
    const int gn = n0 + r;
    ushort8 u;
    if (gn < Vv) {
      const float4 f0 = *(const float4*)&tok[(size_t)gn*Dm + c8];
      const float4 f1 = *(const float4*)&tok[(size_t)gn*Dm + c8 + 4];
      u[0]=f2bf(f0.x); u[1]=f2bf(f0.y); u[2]=f2bf(f0.z); u[3]=f2bf(f0.w);
      u[4]=f2bf(f1.x); u[5]=f2bf(f1.y); u[6]=f2bf(f1.z); u[7]=f2bf(f1.w);
    } else {
      #pragma unroll
      for (int j = 0; j < 8; ++j) u[j] = 0;
    }
    *(ushort8*)&Bp[r][c8] = u;
  }

  const int lane = t & 63, fr = lane & 15, fg = lane >> 4;
  const int wave = t >> 6;          // 0..7, wave tile = rows [wave*32, wave*32+32)
  const int arow = t >> 1;          // 0..255 staging row
  const int acol = (t & 1) * 32;    // 0 or 32
  __syncthreads();

  for (int mi = 0; mi < 8; ++mi) {
    const int row0 = (blockIdx.y * 8 + mi) * 256;
    f32x4 acc[2][4];
    #pragma unroll
    for (int i = 0; i < 2; ++i)
      #pragma unroll
      for (int j = 0; j < 4; ++j)
        #pragma unroll
        for (int r = 0; r < 4; ++r) acc[i][j][r] = 0.0f;

    // prefetch k-step 0
    const unsigned short* asrc = &hbf[(size_t)(row0 + arow)*Dm + acol];
    ushort8 a0 = *(const ushort8*)(asrc);
    ushort8 a1 = *(const ushort8*)(asrc + 8);
    ushort8 a2 = *(const ushort8*)(asrc + 16);
    ushort8 a3 = *(const ushort8*)(asrc + 24);

    for (int ks = 0; ks < 12; ++ks) {
      __syncthreads();   // As free
      #pragma unroll
      for (int i = 0; i < 4; ++i) {
        const int byt = (arow*128 + acol*2 + i*16) ^ ((arow & 7) << 4);
        *(ushort8*)((char*)As + byt) = (i==0) ? a0 : (i==1) ? a1 : (i==2) ? a2 : a3;
      }
      __syncthreads();   // staged
      if (ks < 11) {
        asrc = &hbf[(size_t)(row0 + arow)*Dm + (ks+1)*64 + acol];
        a0 = *(const ushort8*)(asrc);
        a1 = *(const ushort8*)(asrc + 8);
        a2 = *(const ushort8*)(asrc + 16);
        a3 = *(const ushort8*)(asrc + 24);
      }
      const int swz = (fr & 7) << 4;
      #pragma unroll
      for (int kh = 0; kh < 2; ++kh) {
        bf16x8 af[2], bfr[4];
        #pragma unroll
        for (int mt = 0; mt < 2; ++mt)
          af[mt] = *(const bf16x8*)((const char*)As + (((wave*32 + mt*16 + fr)*128 + kh*64 + fg*16) ^ swz));
        #pragma unroll
        for (int nt = 0; nt < 4; ++nt)
          bfr[nt] = *(const bf16x8*)&Bp[nt*16 + fr][ks*64 + kh*32 + fg*8];
        #pragma unroll
        for (int mt = 0; mt < 2; ++mt)
          #pragma unroll
          for (int nt = 0; nt < 4; ++nt)
            acc[mt][nt] = __builtin_amdgcn_mfma_f32_16x16x32_bf16(af[mt], bfr[nt], acc[mt][nt], 0, 0, 0);
      }
    }
    #pragma unroll
    for (int mt = 0; mt < 2; ++mt) {
      #pragma unroll
      for (int nt = 0; nt < 4; ++nt) {
        const int col = n0 + nt*16 + fr;
        if (col < Vv) {
          const int rbase = row0 + wave*32 + mt*16 + fg*4;
          #pragma unroll
          for (int r = 0; r < 4; ++r)
            C[(size_t)(rbase + r) * Vv + col] = acc[mt][nt][r];
        }
      }
    }
  }
}

// ---------------- host-side orchestration ----------------
extern "C" void kernel_launch(void* const* d_in, const int* in_sizes, int n_in,
                              void* d_out, int out_size, void* d_ws, size_t ws_size,
                              hipStream_t stream)
{
  const int*   ids = (const int*)  d_in[0];
  const float* tok = (const float*)d_in[1];
  const float* ew  = (const float*)d_in[2];
  const float* eb  = (const float*)d_in[3];
  const float* wq  = (const float*)d_in[4];
  const float* wk  = (const float*)d_in[5];
  const float* wv  = (const float*)d_in[6];
  const float* wo  = (const float*)d_in[7];
  const float* n1w = (const float*)d_in[8];
  const float* n1b = (const float*)d_in[9];
  const float* n2w = (const float*)d_in[10];
  const float* n2b = (const float*)d_in[11];
  const float* m1w = (const float*)d_in[12];
  const float* m1b = (const float*)d_in[13];
  const float* m2w = (const float*)d_in[14];
  const float* m2b = (const float*)d_in[15];
  const float* onw = (const float*)d_in[16];
  const float* onb = (const float*)d_in[17];

  // ws: x (f32 residual), h (packed u32 / bf16 ushort, reused)
  float* x = (float*)d_ws;
  float* h = x + (size_t)Tt * Dm;
  float* out = (float*)d_out;
  // d_out scratch (all dead before logits writes C):
  uint32_t* g  = (uint32_t*)d_out;              // packed g [4096][3072]
  float* q  = out + (size_t)(1u << 24);
  float* k  = q   + (size_t)(1u << 22);
  float* v  = k   + (size_t)(1u << 22);
  uint32_t* ob = (uint32_t*)(v + (size_t)(1u << 22));
  uint32_t* wpk = (uint32_t*)d_out + 40000000u; // packed weights, 85M u32
  const size_t SQQ = (size_t)Ll * Dm * Dm;      // 7,077,888
  const size_t SMM = (size_t)Ll * Dm * Ff;      // 28,311,552
  uint32_t* wq_pk = wpk;
  uint32_t* wk_pk = wq_pk + SQQ;
  uint32_t* wv_pk = wk_pk + SQQ;
  uint32_t* wo_pk = wv_pk + SQQ;
  uint32_t* m1_pk = wo_pk + SQQ;
  uint32_t* m2_pk = m1_pk + SMM;

  convw_kernel<<<1024, 256, 0, stream>>>(wq, wq_pk, (int)(SQQ/4));
  convw_kernel<<<1024, 256, 0, stream>>>(wk, wk_pk, (int)(SQQ/4));
  convw_kernel<<<1024, 256, 0, stream>>>(wv, wv_pk, (int)(SQQ/4));
  convw_kernel<<<1024, 256, 0, stream>>>(wo, wo_pk, (int)(SQQ/4));
  convw_kernel<<<2048, 256, 0, stream>>>(m1w, m1_pk, (int)(SMM/4));
  convw_kernel<<<2048, 256, 0, stream>>>(m2w, m2_pk, (int)(SMM/4));

  ln_kernel<0><<<Tt, 256, 0, stream>>>(tok, ids, ew, eb, x);

  for (int l = 0; l < Ll; ++l) {
    ln_kernel<1><<<Tt, 256, 0, stream>>>(x, nullptr, n1w + l*Dm, n1b + l*Dm, h);
    gemm_kernel<false,false,false,false><<<dim3(12,64), 256, 0, stream>>>(
        (const uint32_t*)h, wq_pk + (size_t)l*Dm*Dm, nullptr, nullptr, q, Tt, Dm, Dm);
    gemm_kernel<false,false,false,false><<<dim3(12,64), 256, 0, stream>>>(
        (const uint32_t*)h, wk_pk + (size_t)l*Dm*Dm, nullptr, nullptr, k, Tt, Dm, Dm);
    gemm_kernel<false,false,false,false><<<dim3(12,64), 256, 0, stream>>>(
        (const uint32_t*)h, wv_pk + (size_t)l*Dm*Dm, nullptr, nullptr, v, Tt, Dm, Dm);
    rope_kernel<<<6144, 256, 0, stream>>>(q, k);
    ttt_scan_kernel<<<192, 256, 0, stream>>>(q, k, v, ob);
    gemm_kernel<false,false,true,false><<<dim3(12,64), 256, 0, stream>>>(
        ob, wo_pk + (size_t)l*Dm*Dm, nullptr, x, x, Tt, Dm, Dm);
    ln_kernel<1><<<Tt, 256, 0, stream>>>(x, nullptr, n2w + l*Dm, n2b + l*Dm, h);
    gemm_kernel<true,true,false,true><<<dim3(48,64), 256, 0, stream>>>(
        (const uint32_t*)h, m1_pk + (size_t)l*Dm*Ff, m1b + (size_t)l*Ff, nullptr, g, Tt, Ff, Dm);
    gemm_kernel<true,false,true,false><<<dim3(12,64), 256, 0, stream>>>(
        g, m2_pk + (size_t)l*Ff*Dm, m2b + (size_t)l*Dm, x, x, Tt, Dm, Ff);
  }

  ln_kernel<2><<<Tt, 256, 0, stream>>>(x, nullptr, onw, onb, h);
  logits_kernel<<<dim3(786, 2), 512, 0, stream>>>((const unsigned short*)h, tok, out);
}